// Round 8
// baseline (937.332 us; speedup 1.0000x reference)
//
#include <hip/hip_runtime.h>

#define N_NODES 100000
#define N_EDGES 600000
#define NODE_DIM 64
#define EDGE_DIM 32
#define HID 128
#define OUT_DIM 24

typedef short short8 __attribute__((ext_vector_type(8)));
typedef short short4v __attribute__((ext_vector_type(4)));
typedef float f32x4 __attribute__((ext_vector_type(4)));

#define MFMA16(a, b, c) __builtin_amdgcn_mfma_f32_16x16x32_bf16(a, b, c, 0, 0, 0)

__device__ inline unsigned short f2bf(float f) {
  unsigned u = __float_as_uint(f);
  u += 0x7FFFu + ((u >> 16) & 1u);
  return (unsigned short)(u >> 16);
}
__device__ inline float bf2f(unsigned short b) {
  return __uint_as_float(((unsigned)b) << 16);
}

// ---- prepped weight region layout (ushort units) ----
// cls w1 in MFMA B-FRAGMENT order: [chunk c(9)][frag(512)][8]
// cls w2 in frag order: [nt2(2)][kc(4)][lane(64)][8]
#define OFF_CW1T 0                       // cls w1 frag-order bf16 [9][512][8]
#define OFF_CW2T 36864                   // cls w2 frag-order bf16 [512][8]
#define OFF_LAYER(c) (40960 + (c)*65536) // per conv: w1t_hi,w1t_lo,w2t_hi,w2t_lo each [128][128]
#define OFF_EWT(c) (237568 + (c)*8192)   // per conv: ew^T in MFMA B-frag order, hi[4096]+lo[4096]
#define W_TOTAL 262144

__global__ __launch_bounds__(256) void prep_weights(
    const float* __restrict__ cw1, const float* __restrict__ cw2,
    const float* __restrict__ l0w1, const float* __restrict__ l0w2,
    const float* __restrict__ l1w1, const float* __restrict__ l1w2,
    const float* __restrict__ l2w1, const float* __restrict__ l2w2,
    const float* __restrict__ e0w, const float* __restrict__ e1w,
    const float* __restrict__ e2w,
    unsigned short* __restrict__ wb) {
  int i = blockIdx.x * 256 + threadIdx.x;
  if (i < 36864) {                       // cls w1 in B-frag order
    int c = i >> 12, v = i & 4095;       // c = 0..8
    int f = v >> 3, jj = v & 7;
    int t = f >> 6, l = f & 63;
    int n = t * 16 + (l & 15);
    int k = c * 32 + (l >> 4) * 8 + jj;  // 0..287
    wb[OFF_CW1T + i] = f2bf(cw1[k * 128 + n]);
  }
  int j = i - 36864;
  if (j >= 0 && j < 4096) {              // cls w2 in frag order, n padded to 32
    int f = j >> 3, jj = j & 7;
    int nt2 = f >> 8, rem = f & 255;
    int kc = rem >> 6, l = rem & 63;
    int n = nt2 * 16 + (l & 15);
    int k = kc * 32 + (l >> 4) * 8 + jj;
    wb[OFF_CW2T + j] = f2bf(n < 24 ? cw2[k * 24 + n] : 0.f);
  }
  int t = i - 40960;
  if (t >= 0 && t < 3 * 32768) {         // conv layers, split hi/lo
    int c = t / 32768, u = t % 32768;
    const float* w = (u < 16384) ? (c == 0 ? l0w1 : c == 1 ? l1w1 : l2w1)
                                 : (c == 0 ? l0w2 : c == 1 ? l1w2 : l2w2);
    int v = u & 16383;
    int n = v >> 7, k = v & 127;
    float val = w[k * 128 + n];
    unsigned short hi = f2bf(val);
    unsigned short lo = f2bf(val - bf2f(hi));
    int base = OFF_LAYER(c) + (u < 16384 ? 0 : 32768);
    wb[base + v] = hi;
    wb[base + 16384 + v] = lo;
  }
  int p = i - 139264;
  if (p >= 0 && p < 3 * 8192) {          // ew^T in MFMA B-fragment order, hi/lo
    int c = p / 8192, u = p % 8192;
    int v = u & 4095;
    int s = v >> 3, jj = v & 7;
    int ntile = s >> 6, kgrp = (s >> 4) & 3, nrow = s & 15;
    int n = ntile * 16 + nrow, k = kgrp * 8 + jj;
    const float* ew = (c == 0 ? e0w : c == 1 ? e1w : e2w);
    float val = ew[k * 128 + n];
    unsigned short hi = f2bf(val);
    wb[OFF_EWT(c) + u] = (u < 4096) ? hi : f2bf(val - bf2f(hi));
  }
}

// ================= lin1: h = x @ w + b  (K=64, fp32) =================
__global__ __launch_bounds__(256) void lin1_kernel(
    const float* __restrict__ x, const float* __restrict__ w,
    const float* __restrict__ b, float* __restrict__ h,
    unsigned short* __restrict__ hbf) {
  __shared__ float4 smem4[3072];
  float* sA = (float*)smem4;
  float* sB = (float*)smem4 + 4096;
  int tid = threadIdx.x;
  int tn = tid & 31, tm = tid >> 5;
  int mbase = blockIdx.x * 64;

  for (int i = tid; i < 1024; i += 256) {
    int m = i & 63, k4 = (i >> 6) << 2;
    int row = mbase + m; if (row >= N_NODES) row = N_NODES - 1;
    float4 v = *(const float4*)(x + (size_t)row * NODE_DIM + k4);
    sA[(k4 + 0) * 64 + m] = v.x; sA[(k4 + 1) * 64 + m] = v.y;
    sA[(k4 + 2) * 64 + m] = v.z; sA[(k4 + 3) * 64 + m] = v.w;
  }
  for (int i = tid; i < 2048; i += 256)
    *(float4*)&sB[i * 4] = ((const float4*)w)[i];
  __syncthreads();

  float acc[8][4] = {};
#pragma unroll 8
  for (int k = 0; k < 64; ++k) {
    float4 a0 = *(float4*)&sA[k * 64 + tm * 8];
    float4 a1 = *(float4*)&sA[k * 64 + tm * 8 + 4];
    float4 bv = *(float4*)&sB[k * 128 + tn * 4];
    float av[8] = {a0.x, a0.y, a0.z, a0.w, a1.x, a1.y, a1.z, a1.w};
    float bb[4] = {bv.x, bv.y, bv.z, bv.w};
#pragma unroll
    for (int i = 0; i < 8; ++i)
#pragma unroll
      for (int jj = 0; jj < 4; ++jj) acc[i][jj] = fmaf(av[i], bb[jj], acc[i][jj]);
  }
  float4 bv = *(const float4*)(b + tn * 4);
#pragma unroll
  for (int i = 0; i < 8; ++i) {
    int row = mbase + tm * 8 + i;
    if (row < N_NODES) {
      float4 o = {acc[i][0] + bv.x, acc[i][1] + bv.y, acc[i][2] + bv.z, acc[i][3] + bv.w};
      *(float4*)(h + (size_t)row * HID + tn * 4) = o;
      short4v pk = {(short)f2bf(o.x), (short)f2bf(o.y), (short)f2bf(o.z), (short)f2bf(o.w)};
      *(short4v*)(hbf + (size_t)row * HID + tn * 4) = pk;
    }
  }
}

// ======================= CSR build =======================
__global__ __launch_bounds__(256) void hist_kernel(
    const int* __restrict__ dst, int* __restrict__ counts) {
  int e = blockIdx.x * 256 + threadIdx.x;
  if (e < N_EDGES) atomicAdd(&counts[dst[e]], 1);
}

#define SCAN_BLK 98  // ceil(100000/1024)
__global__ __launch_bounds__(256) void scan_partial(
    const int* __restrict__ cnt, int* __restrict__ partial) {
  __shared__ int sdata[256];
  int b = blockIdx.x, t = threadIdx.x;
  int sum = 0;
  for (int i = t; i < 1024; i += 256) {
    int idx = b * 1024 + i;
    sum += (idx < N_NODES) ? cnt[idx] : 0;
  }
  sdata[t] = sum; __syncthreads();
  for (int s = 128; s > 0; s >>= 1) {
    if (t < s) sdata[t] += sdata[t + s];
    __syncthreads();
  }
  if (t == 0) partial[b] = sdata[0];
}

__global__ void scan_sums(const int* __restrict__ partial,
                          int* __restrict__ partialScan, int* __restrict__ rowptr) {
  if (threadIdx.x == 0) {
    int acc = 0;
    for (int i = 0; i < SCAN_BLK; ++i) { partialScan[i] = acc; acc += partial[i]; }
    rowptr[N_NODES] = acc;
  }
}

__global__ __launch_bounds__(256) void scan_final(
    const int* __restrict__ cnt, const int* __restrict__ partialScan,
    int* __restrict__ rowptr, int* __restrict__ cur) {
  __shared__ int sdata[256];
  int b = blockIdx.x, t = threadIdx.x;
  int i0 = b * 1024 + t * 4;
  int c[4]; int s = 0;
#pragma unroll
  for (int j = 0; j < 4; ++j) {
    c[j] = (i0 + j < N_NODES) ? cnt[i0 + j] : 0;
    s += c[j];
  }
  sdata[t] = s; __syncthreads();
  for (int d = 1; d < 256; d <<= 1) {
    int u = (t >= d) ? sdata[t - d] : 0;
    __syncthreads();
    sdata[t] += u;
    __syncthreads();
  }
  int off = sdata[t] - s + partialScan[b];
#pragma unroll
  for (int j = 0; j < 4; ++j) {
    int idx = i0 + j;
    if (idx < N_NODES) { rowptr[idx] = off; cur[idx] = off; off += c[j]; }
  }
}

__global__ __launch_bounds__(256) void scatter_kernel(
    const int* __restrict__ dst, const int* __restrict__ src,
    int* __restrict__ cur, int* __restrict__ perm,
    int* __restrict__ srcp, int* __restrict__ dstp) {
  int e = blockIdx.x * 256 + threadIdx.x;
  if (e < N_EDGES) {
    int d = dst[e];
    int slot = atomicAdd(&cur[d], 1);
    perm[slot] = e;
    srcp[slot] = src[e];
    dstp[slot] = d;
  }
}

// ==== one-time: bf16 ea rows in MFMA A-fragment layout.
// frag  (CSR slot order, for edge_agg): row = ea[perm[slot]]
// frag2 (edge order, for cls):          row = ea[e]            ====
__global__ __launch_bounds__(256) void build_eafrag(
    const float* __restrict__ ea, const int* __restrict__ perm,
    unsigned short* __restrict__ frag, unsigned short* __restrict__ frag2) {
  int i = blockIdx.x * 256 + threadIdx.x;
  if (i >= N_EDGES) return;
  size_t doff = ((size_t)(i >> 7)) * 4096 +
                (size_t)(((i & 127) >> 4)) * 512 + (i & 15) * 8;
  int e = perm[i];
  const float4* rowp = (const float4*)(ea + (size_t)e * EDGE_DIM);
  const float4* rowe = (const float4*)(ea + (size_t)i * EDGE_DIM);
#pragma unroll
  for (int kg = 0; kg < 4; ++kg) {
    float4 v0 = rowp[kg * 2], v1 = rowp[kg * 2 + 1];
    short8 pk = {(short)f2bf(v0.x), (short)f2bf(v0.y), (short)f2bf(v0.z), (short)f2bf(v0.w),
                 (short)f2bf(v1.x), (short)f2bf(v1.y), (short)f2bf(v1.z), (short)f2bf(v1.w)};
    *(short8*)(frag + doff + kg * 128) = pk;
    float4 w0 = rowe[kg * 2], w1 = rowe[kg * 2 + 1];
    short8 pk2 = {(short)f2bf(w0.x), (short)f2bf(w0.y), (short)f2bf(w0.z), (short)f2bf(w0.w),
                  (short)f2bf(w1.x), (short)f2bf(w1.y), (short)f2bf(w1.z), (short)f2bf(w1.w)};
    *(short8*)(frag2 + doff + kg * 128) = pk2;
  }
}

// ==== fused: per 128-slot CSR block: emb = ea@ew+eb (MFMA), m = relu(hbf[src]+emb)
// emb kept bf16 in LDS (33.8 KB -> 4 blocks/CU), in-block segment-sum. ====
__global__ __launch_bounds__(256) void edge_agg_kernel(
    const unsigned short* __restrict__ hbf, const unsigned short* __restrict__ eafrag,
    const int* __restrict__ srcp, const int* __restrict__ dstp,
    const unsigned short* __restrict__ ewt, const float* __restrict__ eb,
    float* __restrict__ agg) {
  __shared__ unsigned short emb[128 * 132];  // bf16, stride 132
  __shared__ int sidx[128];
  __shared__ int sdst[128];
  int tid = threadIdx.x, lane = tid & 63, wave = tid >> 6;
  int wm = wave & 1, wn = wave >> 1;
  int sbase = blockIdx.x * 128;
  int nrows = N_EDGES - sbase; if (nrows > 128) nrows = 128;
  if (tid < 128) {
    int sl = sbase + tid;
    sidx[tid] = (sl < N_EDGES) ? srcp[sl] : 0;
    sdst[tid] = (sl < N_EDGES) ? dstp[sl] : -1;
  }
  __syncthreads();  // sidx ready for early gathers

  // --- issue all h gathers for this wave's 32 rows NOW (hidden under MFMA) ---
  int r0 = wave * 32;
  int cl = (lane & 31) * 4;
  uint2 g[16];
#pragma unroll
  for (int rr = 0; rr < 16; ++rr) {
    int row = r0 + rr * 2 + (lane >> 5);
    g[rr] = *(const uint2*)(hbf + (size_t)sidx[row] * HID + cl);
  }

  // --- MFMA: emb = ea_perm @ ew (hi+lo) ---
  const short8* Af = (const short8*)(eafrag) + (size_t)blockIdx.x * 512;
  const short8* Bh = (const short8*)(ewt);
  const short8* Bl = (const short8*)(ewt + 4096);
  short8 af[4], bh[4], bl[4];
#pragma unroll
  for (int mt = 0; mt < 4; ++mt) af[mt] = Af[(wm * 4 + mt) * 64 + lane];
#pragma unroll
  for (int nt = 0; nt < 4; ++nt) {
    bh[nt] = Bh[(wn * 4 + nt) * 64 + lane];
    bl[nt] = Bl[(wn * 4 + nt) * 64 + lane];
  }
  const f32x4 zf = {0.f, 0.f, 0.f, 0.f};
  f32x4 acc[4][4];
#pragma unroll
  for (int mt = 0; mt < 4; ++mt)
#pragma unroll
    for (int nt = 0; nt < 4; ++nt) {
      acc[mt][nt] = MFMA16(af[mt], bh[nt], zf);
      acc[mt][nt] = MFMA16(af[mt], bl[nt], acc[mt][nt]);
    }
  int q = lane >> 4, r = lane & 15;
#pragma unroll
  for (int nt = 0; nt < 4; ++nt) {
    int n = wn * 64 + nt * 16 + r;
    float ebv = eb[n];
#pragma unroll
    for (int mt = 0; mt < 4; ++mt) {
      int rowb = (wm * 4 + mt) * 16 + q * 4;
#pragma unroll
      for (int i2 = 0; i2 < 4; ++i2)
        emb[(rowb + i2) * 132 + n] = f2bf(acc[mt][nt][i2] + ebv);
    }
  }
  __syncthreads();
  // --- combine: m = relu(h + emb), in place bf16 (h already in regs) ---
#pragma unroll
  for (int rr = 0; rr < 16; ++rr) {
    int row = r0 + rr * 2 + (lane >> 5);
    unsigned* ep = (unsigned*)(emb + row * 132 + cl);
    unsigned e0 = ep[0], e1 = ep[1];
    uint2 u = g[rr];
    float m0 = fmaxf(bf2f((unsigned short)e0) + bf2f((unsigned short)u.x), 0.f);
    float m1 = fmaxf(bf2f((unsigned short)(e0 >> 16)) + bf2f((unsigned short)(u.x >> 16)), 0.f);
    float m2 = fmaxf(bf2f((unsigned short)e1) + bf2f((unsigned short)u.y), 0.f);
    float m3 = fmaxf(bf2f((unsigned short)(e1 >> 16)) + bf2f((unsigned short)(u.y >> 16)), 0.f);
    ep[0] = ((unsigned)f2bf(m1) << 16) | f2bf(m0);
    ep[1] = ((unsigned)f2bf(m3) << 16) | f2bf(m2);
  }
  __syncthreads();
  // --- column-serial segment reduce (2 row-halves x 128 cols) ---
  {
    int hh = tid >> 7;
    int col = tid & 127;
    int rbeg = hh * 64;
    int rend = rbeg + 64; if (rend > nrows) rend = nrows;
    if (rbeg < rend) {
      float a = 0.f;
      int cnode = sdst[rbeg];
      bool atomic_first = true;  // may continue from prev block/half
      for (int rr = rbeg; rr < rend; ++rr) {
        int node = sdst[rr];
        if (node != cnode) {
          if (atomic_first) atomicAdd(&agg[(size_t)cnode * HID + col], a);
          else agg[(size_t)cnode * HID + col] = a;
          a = 0.f; cnode = node; atomic_first = false;
        }
        a += bf2f(emb[rr * 132 + col]);
      }
      atomicAdd(&agg[(size_t)cnode * HID + col], a);  // tail: may continue
    }
  }
}

// ======== fallback aggregation (small-workspace path) ========
__global__ __launch_bounds__(256) void agg_gather_kernel(
    const float* __restrict__ h, const float* __restrict__ ea,
    const int* __restrict__ srcp, const int* __restrict__ perm,
    const int* __restrict__ rowptr,
    const float* __restrict__ ew, const float* __restrict__ eb,
    float* __restrict__ agg) {
  int tid = threadIdx.x, lane = tid & 63;
  int wid = blockIdx.x * 4 + (tid >> 6);
  int nwaves = gridDim.x * 4;
  const float2* ew2 = (const float2*)ew;
  float2 ebv = *(const float2*)(eb + lane * 2);

  for (int node = wid; node < N_NODES; node += nwaves) {
    int beg = rowptr[node], end = rowptr[node + 1];
    float2 acc = {0.f, 0.f};
    for (int i = beg; i < end; ++i) {
      int s0 = srcp[i];
      int e0 = perm[i];
      float2 h0 = *(const float2*)(h + (size_t)s0 * HID + lane * 2);
      const float4* ea0 = (const float4*)(ea + (size_t)e0 * EDGE_DIM);
      float2 m0 = ebv;
#pragma unroll
      for (int k4 = 0; k4 < 8; ++k4) {
        float4 a0 = ea0[k4];
        float a0v[4] = {a0.x, a0.y, a0.z, a0.w};
#pragma unroll
        for (int j = 0; j < 4; ++j) {
          float2 w = ew2[(k4 * 4 + j) * 64 + lane];
          m0.x = fmaf(a0v[j], w.x, m0.x);
          m0.y = fmaf(a0v[j], w.y, m0.y);
        }
      }
      acc.x += fmaxf(m0.x + h0.x, 0.f);
      acc.y += fmaxf(m0.y + h0.y, 0.f);
    }
    *(float2*)(agg + (size_t)node * HID + lane * 2) = acc;
  }
}

// ======== node MLP via split-bf16 MFMA ========
__global__ __launch_bounds__(256) void mlp_mfma(
    const float* __restrict__ h, const float* __restrict__ agg,
    const unsigned short* __restrict__ wl,
    const float* __restrict__ b1, const float* __restrict__ b2,
    float* __restrict__ hout, unsigned short* __restrict__ hbfout) {
  __shared__ unsigned short lds[40960];  // 80 KB
  unsigned short* sAh = lds;
  unsigned short* sAl = lds + 4096;
  unsigned short* sBh = lds + 8192;
  unsigned short* sBl = lds + 12288;
  unsigned short* t1h = lds;
  unsigned short* t1l = lds + 16384;
  unsigned short* sB2h = lds + 32768;
  unsigned short* sB2l = lds + 36864;
  const unsigned short* w1h = wl;
  const unsigned short* w1l = wl + 16384;
  const unsigned short* w2h = wl + 32768;
  const unsigned short* w2l = wl + 49152;
  int tid = threadIdx.x, lane = tid & 63, wave = tid >> 6;
  int wm = wave & 1, wn = wave >> 1;
  int mbase = blockIdx.x * 128;
  const f32x4 zf = {0.f, 0.f, 0.f, 0.f};

  f32x4 acc[4][4];
#pragma unroll
  for (int a = 0; a < 4; ++a)
#pragma unroll
    for (int bq = 0; bq < 4; ++bq) acc[a][bq] = zf;

  for (int c = 0; c < 4; ++c) {
    __syncthreads();
#pragma unroll
    for (int it = 0; it < 4; ++it) {
      int idx = it * 256 + tid;
      int m = idx >> 3, k4 = (idx & 7) * 4;
      int row = mbase + m; if (row >= N_NODES) row = N_NODES - 1;
      size_t g = (size_t)row * HID + c * 32 + k4;
      float4 hv = *(const float4*)(h + g);
      float4 av = *(const float4*)(agg + g);
      float z0 = hv.x + av.x, z1 = hv.y + av.y, z2 = hv.z + av.z, z3 = hv.w + av.w;
      unsigned short h0 = f2bf(z0), h1 = f2bf(z1), h2 = f2bf(z2), h3 = f2bf(z3);
      int slot = ((m >> 4) * 4 + (k4 >> 3)) * 16 + (m & 15);
      int off = slot * 8 + (k4 & 7);
      short4v ph = {(short)h0, (short)h1, (short)h2, (short)h3};
      short4v pl = {(short)f2bf(z0 - bf2f(h0)), (short)f2bf(z1 - bf2f(h1)),
                    (short)f2bf(z2 - bf2f(h2)), (short)f2bf(z3 - bf2f(h3))};
      *(short4v*)(sAh + off) = ph;
      *(short4v*)(sAl + off) = pl;
    }
#pragma unroll
    for (int it = 0; it < 2; ++it) {
      int s = it * 256 + tid;
      int ntile = s >> 6, kgrp = (s >> 4) & 3, nrow = s & 15;
      int goff = (ntile * 16 + nrow) * 128 + c * 32 + kgrp * 8;
      *(short8*)(sBh + s * 8) = *(const short8*)(w1h + goff);
      *(short8*)(sBl + s * 8) = *(const short8*)(w1l + goff);
    }
    __syncthreads();
    short8 ah[4], al[4], bh[4], bl[4];
#pragma unroll
    for (int mt = 0; mt < 4; ++mt) {
      ah[mt] = *(short8*)(sAh + ((wm * 4 + mt) * 64 + lane) * 8);
      al[mt] = *(short8*)(sAl + ((wm * 4 + mt) * 64 + lane) * 8);
    }
#pragma unroll
    for (int nt = 0; nt < 4; ++nt) {
      bh[nt] = *(short8*)(sBh + ((wn * 4 + nt) * 64 + lane) * 8);
      bl[nt] = *(short8*)(sBl + ((wn * 4 + nt) * 64 + lane) * 8);
    }
#pragma unroll
    for (int mt = 0; mt < 4; ++mt)
#pragma unroll
      for (int nt = 0; nt < 4; ++nt) {
        acc[mt][nt] = MFMA16(ah[mt], bh[nt], acc[mt][nt]);
        acc[mt][nt] = MFMA16(ah[mt], bl[nt], acc[mt][nt]);
        acc[mt][nt] = MFMA16(al[mt], bh[nt], acc[mt][nt]);
      }
  }
  __syncthreads();
  int q = lane >> 4, r = lane & 15;
#pragma unroll
  for (int nt = 0; nt < 4; ++nt) {
    int n = wn * 64 + nt * 16 + r;
    float b1v = b1[n];
    int kgrp = n >> 3, jj = n & 7;
#pragma unroll
    for (int mt = 0; mt < 4; ++mt) {
      int mtg = wm * 4 + mt;
#pragma unroll
      for (int i2 = 0; i2 < 4; ++i2) {
        int mrow = q * 4 + i2;
        float val = fmaxf(acc[mt][nt][i2] + b1v, 0.f);
        unsigned short hi = f2bf(val);
        int idx = ((mtg * 16 + kgrp) * 16 + mrow) * 8 + jj;
        t1h[idx] = hi;
        t1l[idx] = f2bf(val - bf2f(hi));
      }
    }
  }

  f32x4 acc2[4][4];
#pragma unroll
  for (int a = 0; a < 4; ++a)
#pragma unroll
    for (int bq = 0; bq < 4; ++bq) acc2[a][bq] = zf;

  for (int kc = 0; kc < 4; ++kc) {
    __syncthreads();
#pragma unroll
    for (int it = 0; it < 2; ++it) {
      int s = it * 256 + tid;
      int ntile = s >> 6, kgrp = (s >> 4) & 3, nrow = s & 15;
      int goff = (ntile * 16 + nrow) * 128 + kc * 32 + kgrp * 8;
      *(short8*)(sB2h + s * 8) = *(const short8*)(w2h + goff);
      *(short8*)(sB2l + s * 8) = *(const short8*)(w2l + goff);
    }
    __syncthreads();
    short8 ah[4], al[4], bh[4], bl[4];
#pragma unroll
    for (int mt = 0; mt < 4; ++mt) {
      int mtg = wm * 4 + mt;
      int idx = ((mtg * 16 + kc * 4 + q) * 16 + r) * 8;
      ah[mt] = *(short8*)(t1h + idx);
      al[mt] = *(short8*)(t1l + idx);
    }
#pragma unroll
    for (int nt = 0; nt < 4; ++nt) {
      bh[nt] = *(short8*)(sB2h + ((wn * 4 + nt) * 64 + lane) * 8);
      bl[nt] = *(short8*)(sB2l + ((wn * 4 + nt) * 64 + lane) * 8);
    }
#pragma unroll
    for (int mt = 0; mt < 4; ++mt)
#pragma unroll
      for (int nt = 0; nt < 4; ++nt) {
        acc2[mt][nt] = MFMA16(ah[mt], bh[nt], acc2[mt][nt]);
        acc2[mt][nt] = MFMA16(ah[mt], bl[nt], acc2[mt][nt]);
        acc2[mt][nt] = MFMA16(al[mt], bh[nt], acc2[mt][nt]);
      }
  }
#pragma unroll
  for (int nt = 0; nt < 4; ++nt) {
    int n = wn * 64 + nt * 16 + r;
    float b2v = b2[n];
#pragma unroll
    for (int mt = 0; mt < 4; ++mt) {
      int mtg = wm * 4 + mt;
#pragma unroll
      for (int i2 = 0; i2 < 4; ++i2) {
        int row = mbase + mtg * 16 + q * 4 + i2;
        if (row < N_NODES) {
          float val = fmaxf(acc2[mt][nt][i2] + b2v, 0.f);
          hout[(size_t)row * HID + n] = val;
          hbfout[(size_t)row * HID + n] = f2bf(val);
        }
      }
    }
  }
}

// ======== classifier, edge order (sequential output), bf16 ea fragments
// loaded direct from global (eafrag2); A gathers double-buffered via regs. ========
__global__ __launch_bounds__(256) void cls_mfma_e(
    const unsigned short* __restrict__ hbf, const unsigned short* __restrict__ eafrag2,
    const int* __restrict__ src, const int* __restrict__ dst,
    const unsigned short* __restrict__ w1f, const unsigned short* __restrict__ w2f,
    const float* __restrict__ b1, const float* __restrict__ b2,
    float* __restrict__ out) {
  __shared__ unsigned short lds[16384];  // 32 KB: A dbuf (2 x 8192) / t1 (16384)
  unsigned short* t1 = lds;
  __shared__ int sidx[256];
  int tid = threadIdx.x, lane = tid & 63, wave = tid >> 6;
  int wm = wave & 1, wn = wave >> 1;
  int q = lane >> 4, r = lane & 15;
  int ebase = blockIdx.x * 128;
  const f32x4 zf = {0.f, 0.f, 0.f, 0.f};

  {
    int e0 = ebase + (tid & 127);
    if (e0 >= N_EDGES) e0 = N_EDGES - 1;
    sidx[tid] = (tid < 128 ? src : dst)[e0];
  }
  __syncthreads();

  f32x4 acc[4][4];
#pragma unroll
  for (int a = 0; a < 4; ++a)
#pragma unroll
    for (int bq = 0; bq < 4; ++bq) acc[a][bq] = zf;

  int sub = tid & 7, mb = tid >> 3;  // 8 lanes per row: contiguous 128 B
  int ch = sub >> 2, kg = sub & 3;

  // prologue: prefetch pair 0 (src h, cols 0..63) + ea fragments (streaming)
  short8 pf[4];
#pragma unroll
  for (int it = 0; it < 4; ++it) {
    int m = it * 32 + mb;
    pf[it] = *(const short8*)(hbf + (size_t)sidx[m] * HID + sub * 8);
  }
  const short8* AfE = (const short8*)(eafrag2) + (size_t)blockIdx.x * 512;
  short8 afE[4];
#pragma unroll
  for (int mt = 0; mt < 4; ++mt) afE[mt] = AfE[(wm * 4 + mt) * 64 + lane];

  for (int cp = 0; cp < 4; ++cp) {
    unsigned short* bufA = lds + (cp & 1) * 8192;
    // write prefetched A into LDS (XOR swizzle: conflict-free)
#pragma unroll
    for (int it = 0; it < 4; ++it) {
      int m = it * 32 + mb;
      *(short8*)(bufA + ch * 4096 +
                 (((m >> 4) * 4 + kg) * 16 + ((m & 15) ^ sub)) * 8) = pf[it];
    }
    // issue next pair's gathers (latency hides under this pair's MFMA)
    if (cp < 3) {
      int ncp = cp + 1;
      int eoff = (ncp & 1) * 64;
#pragma unroll
      for (int it = 0; it < 4; ++it) {
        int m = it * 32 + mb;
        int node = (ncp < 2) ? sidx[m] : sidx[128 + m];
        pf[it] = *(const short8*)(hbf + (size_t)node * HID + eoff + sub * 8);
      }
    }
    __syncthreads();
#pragma unroll
    for (int ch2 = 0; ch2 < 2; ++ch2) {
      int c = cp * 2 + ch2;
      short8 af[4], bfv[4];
#pragma unroll
      for (int nt = 0; nt < 4; ++nt)
        bfv[nt] = *(const short8*)(w1f + (size_t)c * 4096 + ((wn * 4 + nt) * 64 + lane) * 8);
#pragma unroll
      for (int mt = 0; mt < 4; ++mt)
        af[mt] = *(short8*)(bufA + ch2 * 4096 +
                            (((wm * 4 + mt) * 4 + q) * 16 + (r ^ (ch2 * 4 + q))) * 8);
#pragma unroll
      for (int mt = 0; mt < 4; ++mt)
#pragma unroll
        for (int nt = 0; nt < 4; ++nt)
          acc[mt][nt] = MFMA16(af[mt], bfv[nt], acc[mt][nt]);
    }
    // no second barrier: next iteration writes the OTHER buffer
  }
  // ---- ea chunk (c=8): A fragments already in registers, no LDS ----
  {
    short8 bfv[4];
#pragma unroll
    for (int nt = 0; nt < 4; ++nt)
      bfv[nt] = *(const short8*)(w1f + (size_t)8 * 4096 + ((wn * 4 + nt) * 64 + lane) * 8);
#pragma unroll
    for (int mt = 0; mt < 4; ++mt)
#pragma unroll
      for (int nt = 0; nt < 4; ++nt)
        acc[mt][nt] = MFMA16(afE[mt], bfv[nt], acc[mt][nt]);
  }
  __syncthreads();  // before t1 (overlaps A buffers)
#pragma unroll
  for (int nt = 0; nt < 4; ++nt) {
    int n = wn * 64 + nt * 16 + r;
    float b1v = b1[n];
    int kgrp = n >> 3, jj = n & 7;
#pragma unroll
    for (int mt = 0; mt < 4; ++mt) {
      int mtg = wm * 4 + mt;
#pragma unroll
      for (int i2 = 0; i2 < 4; ++i2) {
        int mrow = q * 4 + i2;
        float val = fmaxf(acc[mt][nt][i2] + b1v, 0.f);
        t1[((mtg * 16 + kgrp) * 16 + mrow) * 8 + jj] = f2bf(val);
      }
    }
  }
  __syncthreads();

  f32x4 acc2[2][2];
  acc2[0][0] = zf; acc2[0][1] = zf; acc2[1][0] = zf; acc2[1][1] = zf;
#pragma unroll
  for (int kc = 0; kc < 4; ++kc) {
    short8 a0 = *(short8*)(t1 + (((wave * 2 + 0) * 16 + kc * 4 + q) * 16 + r) * 8);
    short8 a1 = *(short8*)(t1 + (((wave * 2 + 1) * 16 + kc * 4 + q) * 16 + r) * 8);
    short8 b0 = *(const short8*)(w2f + (kc * 64 + lane) * 8);
    short8 b1f = *(const short8*)(w2f + (256 + kc * 64 + lane) * 8);
    acc2[0][0] = MFMA16(a0, b0, acc2[0][0]);
    acc2[0][1] = MFMA16(a0, b1f, acc2[0][1]);
    acc2[1][0] = MFMA16(a1, b0, acc2[1][0]);
    acc2[1][1] = MFMA16(a1, b1f, acc2[1][1]);
  }
#pragma unroll
  for (int nt2 = 0; nt2 < 2; ++nt2) {
    int n = nt2 * 16 + r;
    float b2v = (n < OUT_DIM) ? b2[n] : 0.f;
#pragma unroll
    for (int mt2 = 0; mt2 < 2; ++mt2) {
      int mtg = wave * 2 + mt2;
#pragma unroll
      for (int i2 = 0; i2 < 4; ++i2) {
        int e = ebase + mtg * 16 + q * 4 + i2;
        if (n < OUT_DIM && e < N_EDGES)
          out[(size_t)e * OUT_DIM + n] = acc2[mt2][nt2][i2] + b2v;
      }
    }
  }
}

// ======== fallback classifier (fp32 ea path) ========
__global__ __launch_bounds__(256) void cls_mfma_direct(
    const unsigned short* __restrict__ hbf, const float* __restrict__ ea,
    const int* __restrict__ src, const int* __restrict__ dst,
    const unsigned short* __restrict__ w1f, const unsigned short* __restrict__ w2f,
    const float* __restrict__ b1, const float* __restrict__ b2,
    float* __restrict__ out) {
  __shared__ unsigned short lds[16384];
  unsigned short* t1 = lds;
  __shared__ int sidx[256];
  int tid = threadIdx.x, lane = tid & 63, wave = tid >> 6;
  int wm = wave & 1, wn = wave >> 1;
  int q = lane >> 4, r = lane & 15;
  int ebase = blockIdx.x * 128;
  const f32x4 zf = {0.f, 0.f, 0.f, 0.f};
  {
    int e0 = ebase + (tid & 127);
    if (e0 >= N_EDGES) e0 = N_EDGES - 1;
    sidx[tid] = (tid < 128 ? src : dst)[e0];
  }
  __syncthreads();
  f32x4 acc[4][4];
#pragma unroll
  for (int a = 0; a < 4; ++a)
#pragma unroll
    for (int bq = 0; bq < 4; ++bq) acc[a][bq] = zf;
  int sub = tid & 7, mb = tid >> 3;
  int ch = sub >> 2, kg = sub & 3;
  short8 pf[4];
#pragma unroll
  for (int it = 0; it < 4; ++it) {
    int m = it * 32 + mb;
    pf[it] = *(const short8*)(hbf + (size_t)sidx[m] * HID + sub * 8);
  }
  float4 ef[4];
  for (int cp = 0; cp < 4; ++cp) {
    unsigned short* bufA = lds + (cp & 1) * 8192;
#pragma unroll
    for (int it = 0; it < 4; ++it) {
      int m = it * 32 + mb;
      *(short8*)(bufA + ch * 4096 +
                 (((m >> 4) * 4 + kg) * 16 + ((m & 15) ^ sub)) * 8) = pf[it];
    }
    if (cp < 3) {
      int ncp = cp + 1;
      int eoff = (ncp & 1) * 64;
#pragma unroll
      for (int it = 0; it < 4; ++it) {
        int m = it * 32 + mb;
        int node = (ncp < 2) ? sidx[m] : sidx[128 + m];
        pf[it] = *(const short8*)(hbf + (size_t)node * HID + eoff + sub * 8);
      }
    } else {
#pragma unroll
      for (int it = 0; it < 4; ++it) {
        int m = it * 32 + mb;
        int e8 = ebase + m; if (e8 >= N_EDGES) e8 = N_EDGES - 1;
        ef[it] = *(const float4*)(ea + (size_t)e8 * EDGE_DIM + sub * 4);
      }
    }
    __syncthreads();
#pragma unroll
    for (int ch2 = 0; ch2 < 2; ++ch2) {
      int c = cp * 2 + ch2;
      short8 af[4], bfv[4];
#pragma unroll
      for (int nt = 0; nt < 4; ++nt)
        bfv[nt] = *(const short8*)(w1f + (size_t)c * 4096 + ((wn * 4 + nt) * 64 + lane) * 8);
#pragma unroll
      for (int mt = 0; mt < 4; ++mt)
        af[mt] = *(short8*)(bufA + ch2 * 4096 +
                            (((wm * 4 + mt) * 4 + q) * 16 + (r ^ (ch2 * 4 + q))) * 8);
#pragma unroll
      for (int mt = 0; mt < 4; ++mt)
#pragma unroll
        for (int nt = 0; nt < 4; ++nt)
          acc[mt][nt] = MFMA16(af[mt], bfv[nt], acc[mt][nt]);
    }
  }
  {
    unsigned short* bufA = lds;
    int k4 = sub * 4, kgE = k4 >> 3;
#pragma unroll
    for (int it = 0; it < 4; ++it) {
      int m = it * 32 + mb;
      float4 v = ef[it];
      int slot = ((m >> 4) * 4 + kgE) * 16 + ((m & 15) ^ kgE);
      short4v pk = {(short)f2bf(v.x), (short)f2bf(v.y), (short)f2bf(v.z), (short)f2bf(v.w)};
      *(short4v*)(bufA + slot * 8 + (k4 & 7)) = pk;
    }
    __syncthreads();
    short8 af[4], bfv[4];
#pragma unroll
    for (int nt = 0; nt < 4; ++nt)
      bfv[nt] = *(const short8*)(w1f + (size_t)8 * 4096 + ((wn * 4 + nt) * 64 + lane) * 8);
#pragma unroll
    for (int mt = 0; mt < 4; ++mt)
      af[mt] = *(short8*)(bufA + (((wm * 4 + mt) * 4 + q) * 16 + (r ^ q)) * 8);
#pragma unroll
    for (int mt = 0; mt < 4; ++mt)
#pragma unroll
      for (int nt = 0; nt < 4; ++nt)
        acc[mt][nt] = MFMA16(af[mt], bfv[nt], acc[mt][nt]);
  }
  __syncthreads();
#pragma unroll
  for (int nt = 0; nt < 4; ++nt) {
    int n = wn * 64 + nt * 16 + r;
    float b1v = b1[n];
    int kgrp = n >> 3, jj = n & 7;
#pragma unroll
    for (int mt = 0; mt < 4; ++mt) {
      int mtg = wm * 4 + mt;
#pragma unroll
      for (int i2 = 0; i2 < 4; ++i2) {
        int mrow = q * 4 + i2;
        float val = fmaxf(acc[mt][nt][i2] + b1v, 0.f);
        t1[((mtg * 16 + kgrp) * 16 + mrow) * 8 + jj] = f2bf(val);
      }
    }
  }
  __syncthreads();
  f32x4 acc2[2][2];
  acc2[0][0] = zf; acc2[0][1] = zf; acc2[1][0] = zf; acc2[1][1] = zf;
#pragma unroll
  for (int kc = 0; kc < 4; ++kc) {
    short8 a0 = *(short8*)(t1 + (((wave * 2 + 0) * 16 + kc * 4 + q) * 16 + r) * 8);
    short8 a1 = *(short8*)(t1 + (((wave * 2 + 1) * 16 + kc * 4 + q) * 16 + r) * 8);
    short8 b0 = *(const short8*)(w2f + (kc * 64 + lane) * 8);
    short8 b1f = *(const short8*)(w2f + (256 + kc * 64 + lane) * 8);
    acc2[0][0] = MFMA16(a0, b0, acc2[0][0]);
    acc2[0][1] = MFMA16(a0, b1f, acc2[0][1]);
    acc2[1][0] = MFMA16(a1, b0, acc2[1][0]);
    acc2[1][1] = MFMA16(a1, b1f, acc2[1][1]);
  }
#pragma unroll
  for (int nt2 = 0; nt2 < 2; ++nt2) {
    int n = nt2 * 16 + r;
    float b2v = (n < OUT_DIM) ? b2[n] : 0.f;
#pragma unroll
    for (int mt2 = 0; mt2 < 2; ++mt2) {
      int mtg = wave * 2 + mt2;
#pragma unroll
      for (int i2 = 0; i2 < 4; ++i2) {
        int e = ebase + mtg * 16 + q * 4 + i2;
        if (n < OUT_DIM && e < N_EDGES)
          out[(size_t)e * OUT_DIM + n] = acc2[mt2][nt2][i2] + b2v;
      }
    }
  }
}

extern "C" void kernel_launch(void* const* d_in, const int* in_sizes, int n_in,
                              void* d_out, int out_size, void* d_ws, size_t ws_size,
                              hipStream_t stream) {
  const float* x = (const float*)d_in[0];
  const int* ei = (const int*)d_in[1];
  const float* ea = (const float*)d_in[2];
  const float* lin1_w = (const float*)d_in[3];
  const float* lin1_b = (const float*)d_in[4];
  const int* src = ei;
  const int* dst = ei + N_EDGES;

  const size_t NH = (size_t)N_NODES * HID;
  float* bufA = (float*)d_ws;
  float* bufB = bufA + NH;
  int* ibase = (int*)(bufB + NH);
  int* rowptr = ibase;                 // N_NODES+1
  int* cur = ibase + 100004;           // N_NODES
  int* counts = ibase + 200004;        // N_NODES
  int* perm = ibase + 300004;          // N_EDGES
  int* partial = ibase + 900004;       // 128
  int* partialScan = ibase + 900132;   // 128
  int* srcp = ibase + 900260;          // N_EDGES
  int* dstp = ibase + 1500260;         // N_EDGES
  unsigned short* hbf = (unsigned short*)(ibase + 2100264);  // [N][128] bf16, 16B-aligned
  unsigned short* eafrag = hbf + (size_t)N_NODES * HID;      // [E][32] bf16 frag, CSR order
  unsigned short* eafrag2 = eafrag + (size_t)N_EDGES * EDGE_DIM;  // [E][32] bf16 frag, edge order
  size_t need1 = (size_t)((char*)(eafrag + (size_t)N_EDGES * EDGE_DIM) - (char*)d_ws) +
                 (size_t)W_TOTAL * 2 + 4096;
  size_t need2 = (size_t)((char*)(eafrag2 + (size_t)N_EDGES * EDGE_DIM) - (char*)d_ws) +
                 (size_t)W_TOTAL * 2 + 4096;
  bool big = ws_size >= need1;
  bool big2 = ws_size >= need2;
  // prepped weights at the END of ws
  unsigned short* wbase = (unsigned short*)((((uintptr_t)d_ws + ws_size) - (size_t)W_TOTAL * 2) & ~(uintptr_t)255);

  prep_weights<<<(163840 + 255) / 256, 256, 0, stream>>>(
      (const float*)d_in[23], (const float*)d_in[25],
      (const float*)d_in[7], (const float*)d_in[9],
      (const float*)d_in[13], (const float*)d_in[15],
      (const float*)d_in[19], (const float*)d_in[21],
      (const float*)d_in[5], (const float*)d_in[11], (const float*)d_in[17],
      wbase);

  lin1_kernel<<<(N_NODES + 63) / 64, 256, 0, stream>>>(x, lin1_w, lin1_b, bufA, hbf);

  // ---- CSR build (once; shared by all 3 layers) ----
  hipMemsetAsync(counts, 0, N_NODES * sizeof(int), stream);
  hist_kernel<<<(N_EDGES + 255) / 256, 256, 0, stream>>>(dst, counts);
  scan_partial<<<SCAN_BLK, 256, 0, stream>>>(counts, partial);
  scan_sums<<<1, 64, 0, stream>>>(partial, partialScan, rowptr);
  scan_final<<<SCAN_BLK, 256, 0, stream>>>(counts, partialScan, rowptr, cur);
  scatter_kernel<<<(N_EDGES + 255) / 256, 256, 0, stream>>>(dst, src, cur, perm, srcp, dstp);
  if (big)
    build_eafrag<<<(N_EDGES + 255) / 256, 256, 0, stream>>>(
        ea, perm, eafrag, big2 ? eafrag2 : eafrag);

  float* hcur = bufA;
  float* aux = bufB;
  for (int c = 0; c < 3; ++c) {
    const float* ew = (const float*)d_in[5 + c * 6 + 0];
    const float* eb = (const float*)d_in[5 + c * 6 + 1];
    const float* b1 = (const float*)d_in[5 + c * 6 + 3];
    const float* b2 = (const float*)d_in[5 + c * 6 + 5];
    if (big) {
      hipMemsetAsync(aux, 0, NH * sizeof(float), stream);
      edge_agg_kernel<<<(N_EDGES + 127) / 128, 256, 0, stream>>>(
          hbf, eafrag, srcp, dstp, wbase + OFF_EWT(c), eb, aux);
    } else {
      agg_gather_kernel<<<2048, 256, 0, stream>>>(
          hcur, ea, srcp, perm, rowptr, ew, eb, aux);
    }
    mlp_mfma<<<(N_NODES + 127) / 128, 256, 0, stream>>>(
        hcur, aux, wbase + OFF_LAYER(c), b1, b2, aux, hbf);
    float* tmp = hcur; hcur = aux; aux = tmp;
  }

  const float* cb1 = (const float*)d_in[24];
  const float* cb2 = (const float*)d_in[26];
  if (big2) {
    cls_mfma_e<<<(N_EDGES + 127) / 128, 256, 0, stream>>>(
        hbf, eafrag2, src, dst,
        wbase + OFF_CW1T, wbase + OFF_CW2T, cb1, cb2, (float*)d_out);
  } else {
    cls_mfma_direct<<<(N_EDGES + 127) / 128, 256, 0, stream>>>(
        hbf, ea, src, dst, wbase + OFF_CW1T, wbase + OFF_CW2T, cb1, cb2, (float*)d_out);
  }
}

// Round 9
// 864.183 us; speedup vs baseline: 1.0846x; 1.0846x over previous
//
#include <hip/hip_runtime.h>

#define N_NODES 100000
#define N_EDGES 600000
#define NODE_DIM 64
#define EDGE_DIM 32
#define HID 128
#define OUT_DIM 24

typedef short short8 __attribute__((ext_vector_type(8)));
typedef short short4v __attribute__((ext_vector_type(4)));
typedef float f32x4 __attribute__((ext_vector_type(4)));

#define MFMA16(a, b, c) __builtin_amdgcn_mfma_f32_16x16x32_bf16(a, b, c, 0, 0, 0)

__device__ inline unsigned short f2bf(float f) {
  unsigned u = __float_as_uint(f);
  u += 0x7FFFu + ((u >> 16) & 1u);
  return (unsigned short)(u >> 16);
}
__device__ inline float bf2f(unsigned short b) {
  return __uint_as_float(((unsigned)b) << 16);
}

// ---- prepped weight region layout (ushort units) ----
// cls w1 in MFMA B-FRAGMENT order: [chunk c(9)][frag(512)][8]
// cls w2 in frag order: [nt2(2)][kc(4)][lane(64)][8]
// conv layers: w1h_f, w1l_f, w2h_f, w2l_f each in frag order [kc(4)][frag(512)][8]
#define OFF_CW1T 0                       // cls w1 frag-order bf16 [9][512][8]
#define OFF_CW2T 36864                   // cls w2 frag-order bf16 [512][8]
#define OFF_LAYER(c) (40960 + (c)*65536) // per conv: w1h,w1l,w2h,w2l frag order, 16384 each
#define OFF_EWT(c) (237568 + (c)*8192)   // per conv: ew^T in MFMA B-frag order, hi[4096]+lo[4096]
#define W_TOTAL 262144

__global__ __launch_bounds__(256) void prep_weights(
    const float* __restrict__ cw1, const float* __restrict__ cw2,
    const float* __restrict__ l0w1, const float* __restrict__ l0w2,
    const float* __restrict__ l1w1, const float* __restrict__ l1w2,
    const float* __restrict__ l2w1, const float* __restrict__ l2w2,
    const float* __restrict__ e0w, const float* __restrict__ e1w,
    const float* __restrict__ e2w,
    unsigned short* __restrict__ wb) {
  int i = blockIdx.x * 256 + threadIdx.x;
  if (i < 36864) {                       // cls w1 in B-frag order
    int c = i >> 12, v = i & 4095;       // c = 0..8
    int f = v >> 3, jj = v & 7;
    int t = f >> 6, l = f & 63;
    int n = t * 16 + (l & 15);
    int k = c * 32 + (l >> 4) * 8 + jj;  // 0..287
    wb[OFF_CW1T + i] = f2bf(cw1[k * 128 + n]);
  }
  int j = i - 36864;
  if (j >= 0 && j < 4096) {              // cls w2 in frag order, n padded to 32
    int f = j >> 3, jj = j & 7;
    int nt2 = f >> 8, rem = f & 255;
    int kc = rem >> 6, l = rem & 63;
    int n = nt2 * 16 + (l & 15);
    int k = kc * 32 + (l >> 4) * 8 + jj;
    wb[OFF_CW2T + j] = f2bf(n < 24 ? cw2[k * 24 + n] : 0.f);
  }
  int t = i - 40960;
  if (t >= 0 && t < 3 * 32768) {         // conv layers, B-frag order, split hi/lo
    int c = t / 32768, u = t % 32768;
    const float* w = (u < 16384) ? (c == 0 ? l0w1 : c == 1 ? l1w1 : l2w1)
                                 : (c == 0 ? l0w2 : c == 1 ? l1w2 : l2w2);
    int v = u & 16383;
    int kc = v >> 12, f = (v >> 3) & 511, jj = v & 7;
    int t8 = f >> 6, l = f & 63;
    int n = t8 * 16 + (l & 15);
    int k = kc * 32 + (l >> 4) * 8 + jj;
    float val = w[k * 128 + n];
    unsigned short hi = f2bf(val);
    unsigned short lo = f2bf(val - bf2f(hi));
    int base = OFF_LAYER(c) + (u < 16384 ? 0 : 32768);
    wb[base + v] = hi;
    wb[base + 16384 + v] = lo;
  }
  int p = i - 139264;
  if (p >= 0 && p < 3 * 8192) {          // ew^T in MFMA B-fragment order, hi/lo
    int c = p / 8192, u = p % 8192;
    int v = u & 4095;
    int s = v >> 3, jj = v & 7;
    int ntile = s >> 6, kgrp = (s >> 4) & 3, nrow = s & 15;
    int n = ntile * 16 + nrow, k = kgrp * 8 + jj;
    const float* ew = (c == 0 ? e0w : c == 1 ? e1w : e2w);
    float val = ew[k * 128 + n];
    unsigned short hi = f2bf(val);
    wb[OFF_EWT(c) + u] = (u < 4096) ? hi : f2bf(val - bf2f(hi));
  }
}

// ================= lin1: h = x @ w + b  (K=64, fp32) =================
__global__ __launch_bounds__(256) void lin1_kernel(
    const float* __restrict__ x, const float* __restrict__ w,
    const float* __restrict__ b, float* __restrict__ h,
    unsigned short* __restrict__ hbf) {
  __shared__ float4 smem4[3072];
  float* sA = (float*)smem4;
  float* sB = (float*)smem4 + 4096;
  int tid = threadIdx.x;
  int tn = tid & 31, tm = tid >> 5;
  int mbase = blockIdx.x * 64;

  for (int i = tid; i < 1024; i += 256) {
    int m = i & 63, k4 = (i >> 6) << 2;
    int row = mbase + m; if (row >= N_NODES) row = N_NODES - 1;
    float4 v = *(const float4*)(x + (size_t)row * NODE_DIM + k4);
    sA[(k4 + 0) * 64 + m] = v.x; sA[(k4 + 1) * 64 + m] = v.y;
    sA[(k4 + 2) * 64 + m] = v.z; sA[(k4 + 3) * 64 + m] = v.w;
  }
  for (int i = tid; i < 2048; i += 256)
    *(float4*)&sB[i * 4] = ((const float4*)w)[i];
  __syncthreads();

  float acc[8][4] = {};
#pragma unroll 8
  for (int k = 0; k < 64; ++k) {
    float4 a0 = *(float4*)&sA[k * 64 + tm * 8];
    float4 a1 = *(float4*)&sA[k * 64 + tm * 8 + 4];
    float4 bv = *(float4*)&sB[k * 128 + tn * 4];
    float av[8] = {a0.x, a0.y, a0.z, a0.w, a1.x, a1.y, a1.z, a1.w};
    float bb[4] = {bv.x, bv.y, bv.z, bv.w};
#pragma unroll
    for (int i = 0; i < 8; ++i)
#pragma unroll
      for (int jj = 0; jj < 4; ++jj) acc[i][jj] = fmaf(av[i], bb[jj], acc[i][jj]);
  }
  float4 bv = *(const float4*)(b + tn * 4);
#pragma unroll
  for (int i = 0; i < 8; ++i) {
    int row = mbase + tm * 8 + i;
    if (row < N_NODES) {
      float4 o = {acc[i][0] + bv.x, acc[i][1] + bv.y, acc[i][2] + bv.z, acc[i][3] + bv.w};
      *(float4*)(h + (size_t)row * HID + tn * 4) = o;
      short4v pk = {(short)f2bf(o.x), (short)f2bf(o.y), (short)f2bf(o.z), (short)f2bf(o.w)};
      *(short4v*)(hbf + (size_t)row * HID + tn * 4) = pk;
    }
  }
}

// ======================= CSR build =======================
__global__ __launch_bounds__(256) void hist_kernel(
    const int* __restrict__ dst, int* __restrict__ counts) {
  int e = blockIdx.x * 256 + threadIdx.x;
  if (e < N_EDGES) atomicAdd(&counts[dst[e]], 1);
}

#define SCAN_BLK 98  // ceil(100000/1024)
__global__ __launch_bounds__(256) void scan_partial(
    const int* __restrict__ cnt, int* __restrict__ partial) {
  __shared__ int sdata[256];
  int b = blockIdx.x, t = threadIdx.x;
  int sum = 0;
  for (int i = t; i < 1024; i += 256) {
    int idx = b * 1024 + i;
    sum += (idx < N_NODES) ? cnt[idx] : 0;
  }
  sdata[t] = sum; __syncthreads();
  for (int s = 128; s > 0; s >>= 1) {
    if (t < s) sdata[t] += sdata[t + s];
    __syncthreads();
  }
  if (t == 0) partial[b] = sdata[0];
}

__global__ void scan_sums(const int* __restrict__ partial,
                          int* __restrict__ partialScan, int* __restrict__ rowptr) {
  if (threadIdx.x == 0) {
    int acc = 0;
    for (int i = 0; i < SCAN_BLK; ++i) { partialScan[i] = acc; acc += partial[i]; }
    rowptr[N_NODES] = acc;
  }
}

__global__ __launch_bounds__(256) void scan_final(
    const int* __restrict__ cnt, const int* __restrict__ partialScan,
    int* __restrict__ rowptr, int* __restrict__ cur) {
  __shared__ int sdata[256];
  int b = blockIdx.x, t = threadIdx.x;
  int i0 = b * 1024 + t * 4;
  int c[4]; int s = 0;
#pragma unroll
  for (int j = 0; j < 4; ++j) {
    c[j] = (i0 + j < N_NODES) ? cnt[i0 + j] : 0;
    s += c[j];
  }
  sdata[t] = s; __syncthreads();
  for (int d = 1; d < 256; d <<= 1) {
    int u = (t >= d) ? sdata[t - d] : 0;
    __syncthreads();
    sdata[t] += u;
    __syncthreads();
  }
  int off = sdata[t] - s + partialScan[b];
#pragma unroll
  for (int j = 0; j < 4; ++j) {
    int idx = i0 + j;
    if (idx < N_NODES) { rowptr[idx] = off; cur[idx] = off; off += c[j]; }
  }
}

__global__ __launch_bounds__(256) void scatter_kernel(
    const int* __restrict__ dst, const int* __restrict__ src,
    int* __restrict__ cur, int* __restrict__ perm,
    int* __restrict__ srcp, int* __restrict__ dstp) {
  int e = blockIdx.x * 256 + threadIdx.x;
  if (e < N_EDGES) {
    int d = dst[e];
    int slot = atomicAdd(&cur[d], 1);
    perm[slot] = e;
    srcp[slot] = src[e];
    dstp[slot] = d;
  }
}

// ==== one-time: ea rows, permuted to CSR slot order, packed in MFMA
// A-fragment layout (bf16) — consumed by edge_agg ====
__global__ __launch_bounds__(256) void build_eafrag(
    const float* __restrict__ ea, const int* __restrict__ perm,
    unsigned short* __restrict__ frag) {
  int slot = blockIdx.x * 256 + threadIdx.x;
  if (slot >= N_EDGES) return;
  int e = perm[slot];
  const float4* row = (const float4*)(ea + (size_t)e * EDGE_DIM);
  unsigned short* dp = frag + ((size_t)(slot >> 7)) * 4096 +
                       (size_t)(((slot & 127) >> 4)) * 512 + (slot & 15) * 8;
#pragma unroll
  for (int kg = 0; kg < 4; ++kg) {
    float4 v0 = row[kg * 2], v1 = row[kg * 2 + 1];
    short8 pk = {(short)f2bf(v0.x), (short)f2bf(v0.y), (short)f2bf(v0.z), (short)f2bf(v0.w),
                 (short)f2bf(v1.x), (short)f2bf(v1.y), (short)f2bf(v1.z), (short)f2bf(v1.w)};
    *(short8*)(dp + kg * 128) = pk;
  }
}

// ==== fused: per 128-slot CSR block: emb = ea@ew+eb (MFMA), m = relu(hbf[src]+emb)
// emb kept bf16 in LDS (33.8 KB -> 4 blocks/CU), in-block segment-sum. ====
__global__ __launch_bounds__(256) void edge_agg_kernel(
    const unsigned short* __restrict__ hbf, const unsigned short* __restrict__ eafrag,
    const int* __restrict__ srcp, const int* __restrict__ dstp,
    const unsigned short* __restrict__ ewt, const float* __restrict__ eb,
    float* __restrict__ agg) {
  __shared__ unsigned short emb[128 * 132];  // bf16, stride 132
  __shared__ int sidx[128];
  __shared__ int sdst[128];
  int tid = threadIdx.x, lane = tid & 63, wave = tid >> 6;
  int wm = wave & 1, wn = wave >> 1;
  int sbase = blockIdx.x * 128;
  int nrows = N_EDGES - sbase; if (nrows > 128) nrows = 128;
  if (tid < 128) {
    int sl = sbase + tid;
    sidx[tid] = (sl < N_EDGES) ? srcp[sl] : 0;
    sdst[tid] = (sl < N_EDGES) ? dstp[sl] : -1;
  }
  __syncthreads();  // sidx ready for early gathers

  // --- issue all h gathers for this wave's 32 rows NOW (hidden under MFMA) ---
  int r0 = wave * 32;
  int cl = (lane & 31) * 4;
  uint2 g[16];
#pragma unroll
  for (int rr = 0; rr < 16; ++rr) {
    int row = r0 + rr * 2 + (lane >> 5);
    g[rr] = *(const uint2*)(hbf + (size_t)sidx[row] * HID + cl);
  }

  // --- MFMA: emb = ea_perm @ ew (hi+lo) ---
  const short8* Af = (const short8*)(eafrag) + (size_t)blockIdx.x * 512;
  const short8* Bh = (const short8*)(ewt);
  const short8* Bl = (const short8*)(ewt + 4096);
  short8 af[4], bh[4], bl[4];
#pragma unroll
  for (int mt = 0; mt < 4; ++mt) af[mt] = Af[(wm * 4 + mt) * 64 + lane];
#pragma unroll
  for (int nt = 0; nt < 4; ++nt) {
    bh[nt] = Bh[(wn * 4 + nt) * 64 + lane];
    bl[nt] = Bl[(wn * 4 + nt) * 64 + lane];
  }
  const f32x4 zf = {0.f, 0.f, 0.f, 0.f};
  f32x4 acc[4][4];
#pragma unroll
  for (int mt = 0; mt < 4; ++mt)
#pragma unroll
    for (int nt = 0; nt < 4; ++nt) {
      acc[mt][nt] = MFMA16(af[mt], bh[nt], zf);
      acc[mt][nt] = MFMA16(af[mt], bl[nt], acc[mt][nt]);
    }
  int q = lane >> 4, r = lane & 15;
#pragma unroll
  for (int nt = 0; nt < 4; ++nt) {
    int n = wn * 64 + nt * 16 + r;
    float ebv = eb[n];
#pragma unroll
    for (int mt = 0; mt < 4; ++mt) {
      int rowb = (wm * 4 + mt) * 16 + q * 4;
#pragma unroll
      for (int i2 = 0; i2 < 4; ++i2)
        emb[(rowb + i2) * 132 + n] = f2bf(acc[mt][nt][i2] + ebv);
    }
  }
  __syncthreads();
  // --- combine: m = relu(h + emb), in place bf16 (h already in regs) ---
#pragma unroll
  for (int rr = 0; rr < 16; ++rr) {
    int row = r0 + rr * 2 + (lane >> 5);
    unsigned* ep = (unsigned*)(emb + row * 132 + cl);
    unsigned e0 = ep[0], e1 = ep[1];
    uint2 u = g[rr];
    float m0 = fmaxf(bf2f((unsigned short)e0) + bf2f((unsigned short)u.x), 0.f);
    float m1 = fmaxf(bf2f((unsigned short)(e0 >> 16)) + bf2f((unsigned short)(u.x >> 16)), 0.f);
    float m2 = fmaxf(bf2f((unsigned short)e1) + bf2f((unsigned short)u.y), 0.f);
    float m3 = fmaxf(bf2f((unsigned short)(e1 >> 16)) + bf2f((unsigned short)(u.y >> 16)), 0.f);
    ep[0] = ((unsigned)f2bf(m1) << 16) | f2bf(m0);
    ep[1] = ((unsigned)f2bf(m3) << 16) | f2bf(m2);
  }
  __syncthreads();
  // --- column-serial segment reduce (2 row-halves x 128 cols) ---
  {
    int hh = tid >> 7;
    int col = tid & 127;
    int rbeg = hh * 64;
    int rend = rbeg + 64; if (rend > nrows) rend = nrows;
    if (rbeg < rend) {
      float a = 0.f;
      int cnode = sdst[rbeg];
      bool atomic_first = true;  // may continue from prev block/half
      for (int rr = rbeg; rr < rend; ++rr) {
        int node = sdst[rr];
        if (node != cnode) {
          if (atomic_first) atomicAdd(&agg[(size_t)cnode * HID + col], a);
          else agg[(size_t)cnode * HID + col] = a;
          a = 0.f; cnode = node; atomic_first = false;
        }
        a += bf2f(emb[rr * 132 + col]);
      }
      atomicAdd(&agg[(size_t)cnode * HID + col], a);  // tail: may continue
    }
  }
}

// ======== fallback aggregation (small-workspace path) ========
__global__ __launch_bounds__(256) void agg_gather_kernel(
    const float* __restrict__ h, const float* __restrict__ ea,
    const int* __restrict__ srcp, const int* __restrict__ perm,
    const int* __restrict__ rowptr,
    const float* __restrict__ ew, const float* __restrict__ eb,
    float* __restrict__ agg) {
  int tid = threadIdx.x, lane = tid & 63;
  int wid = blockIdx.x * 4 + (tid >> 6);
  int nwaves = gridDim.x * 4;
  const float2* ew2 = (const float2*)ew;
  float2 ebv = *(const float2*)(eb + lane * 2);

  for (int node = wid; node < N_NODES; node += nwaves) {
    int beg = rowptr[node], end = rowptr[node + 1];
    float2 acc = {0.f, 0.f};
    for (int i = beg; i < end; ++i) {
      int s0 = srcp[i];
      int e0 = perm[i];
      float2 h0 = *(const float2*)(h + (size_t)s0 * HID + lane * 2);
      const float4* ea0 = (const float4*)(ea + (size_t)e0 * EDGE_DIM);
      float2 m0 = ebv;
#pragma unroll
      for (int k4 = 0; k4 < 8; ++k4) {
        float4 a0 = ea0[k4];
        float a0v[4] = {a0.x, a0.y, a0.z, a0.w};
#pragma unroll
        for (int j = 0; j < 4; ++j) {
          float2 w = ew2[(k4 * 4 + j) * 64 + lane];
          m0.x = fmaf(a0v[j], w.x, m0.x);
          m0.y = fmaf(a0v[j], w.y, m0.y);
        }
      }
      acc.x += fmaxf(m0.x + h0.x, 0.f);
      acc.y += fmaxf(m0.y + h0.y, 0.f);
    }
    *(float2*)(agg + (size_t)node * HID + lane * 2) = acc;
  }
}

// ======== node MLP via split-bf16 MFMA; B fragments direct from global
// (frag-order prepack) — no B LDS staging, GEMM2 barrier-free. LDS 64 KB. ========
__global__ __launch_bounds__(256) void mlp_mfma(
    const float* __restrict__ h, const float* __restrict__ agg,
    const unsigned short* __restrict__ wl,
    const float* __restrict__ b1, const float* __restrict__ b2,
    float* __restrict__ hout, unsigned short* __restrict__ hbfout) {
  __shared__ unsigned short lds[32768];  // 64 KB
  unsigned short* sAh = lds;             // [0,4096)   during GEMM1
  unsigned short* sAl = lds + 4096;      // [4096,8192)
  unsigned short* t1h = lds;             // [0,16384)  after GEMM1
  unsigned short* t1l = lds + 16384;     // [16384,32768)
  const unsigned short* w1h = wl;            // frag order [4][512][8]
  const unsigned short* w1l = wl + 16384;
  const unsigned short* w2h = wl + 32768;
  const unsigned short* w2l = wl + 49152;
  int tid = threadIdx.x, lane = tid & 63, wave = tid >> 6;
  int wm = wave & 1, wn = wave >> 1;
  int mbase = blockIdx.x * 128;
  const f32x4 zf = {0.f, 0.f, 0.f, 0.f};

  f32x4 acc[4][4];
#pragma unroll
  for (int a = 0; a < 4; ++a)
#pragma unroll
    for (int bq = 0; bq < 4; ++bq) acc[a][bq] = zf;

  for (int c = 0; c < 4; ++c) {
    __syncthreads();
#pragma unroll
    for (int it = 0; it < 4; ++it) {
      int idx = it * 256 + tid;
      int m = idx >> 3, k4 = (idx & 7) * 4;
      int row = mbase + m; if (row >= N_NODES) row = N_NODES - 1;
      size_t g = (size_t)row * HID + c * 32 + k4;
      float4 hv = *(const float4*)(h + g);
      float4 av = *(const float4*)(agg + g);
      float z0 = hv.x + av.x, z1 = hv.y + av.y, z2 = hv.z + av.z, z3 = hv.w + av.w;
      unsigned short h0 = f2bf(z0), h1 = f2bf(z1), h2 = f2bf(z2), h3 = f2bf(z3);
      int slot = ((m >> 4) * 4 + (k4 >> 3)) * 16 + (m & 15);
      int off = slot * 8 + (k4 & 7);
      short4v ph = {(short)h0, (short)h1, (short)h2, (short)h3};
      short4v pl = {(short)f2bf(z0 - bf2f(h0)), (short)f2bf(z1 - bf2f(h1)),
                    (short)f2bf(z2 - bf2f(h2)), (short)f2bf(z3 - bf2f(h3))};
      *(short4v*)(sAh + off) = ph;
      *(short4v*)(sAl + off) = pl;
    }
    __syncthreads();
    short8 ah[4], al[4], bh[4], bl[4];
#pragma unroll
    for (int nt = 0; nt < 4; ++nt) {
      int fo = c * 4096 + ((wn * 4 + nt) * 64 + lane) * 8;
      bh[nt] = *(const short8*)(w1h + fo);
      bl[nt] = *(const short8*)(w1l + fo);
    }
#pragma unroll
    for (int mt = 0; mt < 4; ++mt) {
      ah[mt] = *(short8*)(sAh + ((wm * 4 + mt) * 64 + lane) * 8);
      al[mt] = *(short8*)(sAl + ((wm * 4 + mt) * 64 + lane) * 8);
    }
#pragma unroll
    for (int mt = 0; mt < 4; ++mt)
#pragma unroll
      for (int nt = 0; nt < 4; ++nt) {
        acc[mt][nt] = MFMA16(ah[mt], bh[nt], acc[mt][nt]);
        acc[mt][nt] = MFMA16(ah[mt], bl[nt], acc[mt][nt]);
        acc[mt][nt] = MFMA16(al[mt], bh[nt], acc[mt][nt]);
      }
  }
  __syncthreads();
  int q = lane >> 4, r = lane & 15;
#pragma unroll
  for (int nt = 0; nt < 4; ++nt) {
    int n = wn * 64 + nt * 16 + r;
    float b1v = b1[n];
    int kgrp = n >> 3, jj = n & 7;
#pragma unroll
    for (int mt = 0; mt < 4; ++mt) {
      int mtg = wm * 4 + mt;
#pragma unroll
      for (int i2 = 0; i2 < 4; ++i2) {
        int mrow = q * 4 + i2;
        float val = fmaxf(acc[mt][nt][i2] + b1v, 0.f);
        unsigned short hi = f2bf(val);
        int idx = ((mtg * 16 + kgrp) * 16 + mrow) * 8 + jj;
        t1h[idx] = hi;
        t1l[idx] = f2bf(val - bf2f(hi));
      }
    }
  }
  __syncthreads();

  f32x4 acc2[4][4];
#pragma unroll
  for (int a = 0; a < 4; ++a)
#pragma unroll
    for (int bq = 0; bq < 4; ++bq) acc2[a][bq] = zf;

  for (int kc = 0; kc < 4; ++kc) {   // no barriers: t1 read-only, B from global
    short8 ah[4], al[4], bh[4], bl[4];
#pragma unroll
    for (int nt = 0; nt < 4; ++nt) {
      int fo = kc * 4096 + ((wn * 4 + nt) * 64 + lane) * 8;
      bh[nt] = *(const short8*)(w2h + fo);
      bl[nt] = *(const short8*)(w2l + fo);
    }
#pragma unroll
    for (int mt = 0; mt < 4; ++mt) {
      int mtg = wm * 4 + mt;
      int idx = ((mtg * 16 + kc * 4 + q) * 16 + r) * 8;
      ah[mt] = *(short8*)(t1h + idx);
      al[mt] = *(short8*)(t1l + idx);
    }
#pragma unroll
    for (int mt = 0; mt < 4; ++mt)
#pragma unroll
      for (int nt = 0; nt < 4; ++nt) {
        acc2[mt][nt] = MFMA16(ah[mt], bh[nt], acc2[mt][nt]);
        acc2[mt][nt] = MFMA16(ah[mt], bl[nt], acc2[mt][nt]);
        acc2[mt][nt] = MFMA16(al[mt], bh[nt], acc2[mt][nt]);
      }
  }
#pragma unroll
  for (int nt = 0; nt < 4; ++nt) {
    int n = wn * 64 + nt * 16 + r;
    float b2v = b2[n];
#pragma unroll
    for (int mt = 0; mt < 4; ++mt) {
      int mtg = wm * 4 + mt;
#pragma unroll
      for (int i2 = 0; i2 < 4; ++i2) {
        int row = mbase + mtg * 16 + q * 4 + i2;
        if (row < N_NODES) {
          float val = fmaxf(acc2[mt][nt][i2] + b2v, 0.f);
          hout[(size_t)row * HID + n] = val;
          hbfout[(size_t)row * HID + n] = f2bf(val);
        }
      }
    }
  }
}

// ======== classifier (round-6 version): edge order, fp32 ea staged at cp=3,
// A gathers double-buffered via registers, B fragments direct from global. ========
__global__ __launch_bounds__(256) void cls_mfma(
    const unsigned short* __restrict__ hbf, const float* __restrict__ ea,
    const int* __restrict__ src, const int* __restrict__ dst,
    const unsigned short* __restrict__ w1f, const unsigned short* __restrict__ w2f,
    const float* __restrict__ b1, const float* __restrict__ b2,
    float* __restrict__ out) {
  __shared__ unsigned short lds[16384];  // 32 KB: A dbuf (2 x 8192) / t1 (16384)
  unsigned short* t1 = lds;
  __shared__ int sidx[256];
  int tid = threadIdx.x, lane = tid & 63, wave = tid >> 6;
  int wm = wave & 1, wn = wave >> 1;
  int q = lane >> 4, r = lane & 15;
  int ebase = blockIdx.x * 128;
  const f32x4 zf = {0.f, 0.f, 0.f, 0.f};

  {
    int e0 = ebase + (tid & 127);
    if (e0 >= N_EDGES) e0 = N_EDGES - 1;
    sidx[tid] = (tid < 128 ? src : dst)[e0];
  }
  __syncthreads();

  f32x4 acc[4][4];
#pragma unroll
  for (int a = 0; a < 4; ++a)
#pragma unroll
    for (int bq = 0; bq < 4; ++bq) acc[a][bq] = zf;

  int sub = tid & 7, mb = tid >> 3;  // 8 lanes per row: contiguous 128 B
  int ch = sub >> 2, kg = sub & 3;

  // prologue: prefetch pair 0 (src h, cols 0..63)
  short8 pf[4];
#pragma unroll
  for (int it = 0; it < 4; ++it) {
    int m = it * 32 + mb;
    pf[it] = *(const short8*)(hbf + (size_t)sidx[m] * HID + sub * 8);
  }
  float4 ef[4];

  for (int cp = 0; cp < 4; ++cp) {
    unsigned short* bufA = lds + (cp & 1) * 8192;
    // write prefetched A into LDS (XOR swizzle: conflict-free)
#pragma unroll
    for (int it = 0; it < 4; ++it) {
      int m = it * 32 + mb;
      *(short8*)(bufA + ch * 4096 +
                 (((m >> 4) * 4 + kg) * 16 + ((m & 15) ^ sub)) * 8) = pf[it];
    }
    // issue next pair's gathers (latency hides under this pair's MFMA)
    if (cp < 3) {
      int ncp = cp + 1;
      int eoff = (ncp & 1) * 64;
#pragma unroll
      for (int it = 0; it < 4; ++it) {
        int m = it * 32 + mb;
        int node = (ncp < 2) ? sidx[m] : sidx[128 + m];
        pf[it] = *(const short8*)(hbf + (size_t)node * HID + eoff + sub * 8);
      }
    } else {
#pragma unroll
      for (int it = 0; it < 4; ++it) {
        int m = it * 32 + mb;
        int e8 = ebase + m; if (e8 >= N_EDGES) e8 = N_EDGES - 1;
        ef[it] = *(const float4*)(ea + (size_t)e8 * EDGE_DIM + sub * 4);
      }
    }
    __syncthreads();
#pragma unroll
    for (int ch2 = 0; ch2 < 2; ++ch2) {
      int c = cp * 2 + ch2;
      short8 af[4], bfv[4];
#pragma unroll
      for (int nt = 0; nt < 4; ++nt)
        bfv[nt] = *(const short8*)(w1f + (size_t)c * 4096 + ((wn * 4 + nt) * 64 + lane) * 8);
#pragma unroll
      for (int mt = 0; mt < 4; ++mt)
        af[mt] = *(short8*)(bufA + ch2 * 4096 +
                            (((wm * 4 + mt) * 4 + q) * 16 + (r ^ (ch2 * 4 + q))) * 8);
#pragma unroll
      for (int mt = 0; mt < 4; ++mt)
#pragma unroll
        for (int nt = 0; nt < 4; ++nt)
          acc[mt][nt] = MFMA16(af[mt], bfv[nt], acc[mt][nt]);
    }
    // no second barrier: next iteration writes the OTHER buffer
  }
  // ---- ea chunk (c=8), into buf 0 (last read at cp=2, fenced by cp=3 barrier) ----
  {
    unsigned short* bufA = lds;
    int k4 = sub * 4, kgE = k4 >> 3;
#pragma unroll
    for (int it = 0; it < 4; ++it) {
      int m = it * 32 + mb;
      float4 v = ef[it];
      int slot = ((m >> 4) * 4 + kgE) * 16 + ((m & 15) ^ kgE);
      short4v pk = {(short)f2bf(v.x), (short)f2bf(v.y), (short)f2bf(v.z), (short)f2bf(v.w)};
      *(short4v*)(bufA + slot * 8 + (k4 & 7)) = pk;
    }
    __syncthreads();
    short8 af[4], bfv[4];
#pragma unroll
    for (int nt = 0; nt < 4; ++nt)
      bfv[nt] = *(const short8*)(w1f + (size_t)8 * 4096 + ((wn * 4 + nt) * 64 + lane) * 8);
#pragma unroll
    for (int mt = 0; mt < 4; ++mt)
      af[mt] = *(short8*)(bufA + (((wm * 4 + mt) * 4 + q) * 16 + (r ^ q)) * 8);
#pragma unroll
    for (int mt = 0; mt < 4; ++mt)
#pragma unroll
      for (int nt = 0; nt < 4; ++nt)
        acc[mt][nt] = MFMA16(af[mt], bfv[nt], acc[mt][nt]);
  }
  __syncthreads();  // before t1 (overlaps A buffers)
#pragma unroll
  for (int nt = 0; nt < 4; ++nt) {
    int n = wn * 64 + nt * 16 + r;
    float b1v = b1[n];
    int kgrp = n >> 3, jj = n & 7;
#pragma unroll
    for (int mt = 0; mt < 4; ++mt) {
      int mtg = wm * 4 + mt;
#pragma unroll
      for (int i2 = 0; i2 < 4; ++i2) {
        int mrow = q * 4 + i2;
        float val = fmaxf(acc[mt][nt][i2] + b1v, 0.f);
        t1[((mtg * 16 + kgrp) * 16 + mrow) * 8 + jj] = f2bf(val);
      }
    }
  }
  __syncthreads();

  f32x4 acc2[2][2];
  acc2[0][0] = zf; acc2[0][1] = zf; acc2[1][0] = zf; acc2[1][1] = zf;
#pragma unroll
  for (int kc = 0; kc < 4; ++kc) {
    short8 a0 = *(short8*)(t1 + (((wave * 2 + 0) * 16 + kc * 4 + q) * 16 + r) * 8);
    short8 a1 = *(short8*)(t1 + (((wave * 2 + 1) * 16 + kc * 4 + q) * 16 + r) * 8);
    short8 b0 = *(const short8*)(w2f + (kc * 64 + lane) * 8);
    short8 b1f = *(const short8*)(w2f + (256 + kc * 64 + lane) * 8);
    acc2[0][0] = MFMA16(a0, b0, acc2[0][0]);
    acc2[0][1] = MFMA16(a0, b1f, acc2[0][1]);
    acc2[1][0] = MFMA16(a1, b0, acc2[1][0]);
    acc2[1][1] = MFMA16(a1, b1f, acc2[1][1]);
  }
#pragma unroll
  for (int nt2 = 0; nt2 < 2; ++nt2) {
    int n = nt2 * 16 + r;
    float b2v = (n < OUT_DIM) ? b2[n] : 0.f;
#pragma unroll
    for (int mt2 = 0; mt2 < 2; ++mt2) {
      int mtg = wave * 2 + mt2;
#pragma unroll
      for (int i2 = 0; i2 < 4; ++i2) {
        int e = ebase + mtg * 16 + q * 4 + i2;
        if (n < OUT_DIM && e < N_EDGES)
          out[(size_t)e * OUT_DIM + n] = acc2[mt2][nt2][i2] + b2v;
      }
    }
  }
}

extern "C" void kernel_launch(void* const* d_in, const int* in_sizes, int n_in,
                              void* d_out, int out_size, void* d_ws, size_t ws_size,
                              hipStream_t stream) {
  const float* x = (const float*)d_in[0];
  const int* ei = (const int*)d_in[1];
  const float* ea = (const float*)d_in[2];
  const float* lin1_w = (const float*)d_in[3];
  const float* lin1_b = (const float*)d_in[4];
  const int* src = ei;
  const int* dst = ei + N_EDGES;

  const size_t NH = (size_t)N_NODES * HID;
  float* bufA = (float*)d_ws;
  float* bufB = bufA + NH;
  int* ibase = (int*)(bufB + NH);
  int* rowptr = ibase;                 // N_NODES+1
  int* cur = ibase + 100004;           // N_NODES
  int* counts = ibase + 200004;        // N_NODES
  int* perm = ibase + 300004;          // N_EDGES
  int* partial = ibase + 900004;       // 128
  int* partialScan = ibase + 900132;   // 128
  int* srcp = ibase + 900260;          // N_EDGES
  int* dstp = ibase + 1500260;         // N_EDGES
  unsigned short* hbf = (unsigned short*)(ibase + 2100264);  // [N][128] bf16, 16B-aligned
  unsigned short* eafrag = hbf + (size_t)N_NODES * HID;      // [E][32] bf16 frag, CSR order
  size_t need = (size_t)((char*)(eafrag + (size_t)N_EDGES * EDGE_DIM) - (char*)d_ws) +
                (size_t)W_TOTAL * 2 + 4096;
  bool big = ws_size >= need;
  // prepped weights at the END of ws
  unsigned short* wbase = (unsigned short*)((((uintptr_t)d_ws + ws_size) - (size_t)W_TOTAL * 2) & ~(uintptr_t)255);

  prep_weights<<<(163840 + 255) / 256, 256, 0, stream>>>(
      (const float*)d_in[23], (const float*)d_in[25],
      (const float*)d_in[7], (const float*)d_in[9],
      (const float*)d_in[13], (const float*)d_in[15],
      (const float*)d_in[19], (const float*)d_in[21],
      (const float*)d_in[5], (const float*)d_in[11], (const float*)d_in[17],
      wbase);

  lin1_kernel<<<(N_NODES + 63) / 64, 256, 0, stream>>>(x, lin1_w, lin1_b, bufA, hbf);

  // ---- CSR build (once; shared by all 3 layers) ----
  hipMemsetAsync(counts, 0, N_NODES * sizeof(int), stream);
  hist_kernel<<<(N_EDGES + 255) / 256, 256, 0, stream>>>(dst, counts);
  scan_partial<<<SCAN_BLK, 256, 0, stream>>>(counts, partial);
  scan_sums<<<1, 64, 0, stream>>>(partial, partialScan, rowptr);
  scan_final<<<SCAN_BLK, 256, 0, stream>>>(counts, partialScan, rowptr, cur);
  scatter_kernel<<<(N_EDGES + 255) / 256, 256, 0, stream>>>(dst, src, cur, perm, srcp, dstp);
  if (big)
    build_eafrag<<<(N_EDGES + 255) / 256, 256, 0, stream>>>(ea, perm, eafrag);

  float* hcur = bufA;
  float* aux = bufB;
  for (int c = 0; c < 3; ++c) {
    const float* ew = (const float*)d_in[5 + c * 6 + 0];
    const float* eb = (const float*)d_in[5 + c * 6 + 1];
    const float* b1 = (const float*)d_in[5 + c * 6 + 3];
    const float* b2 = (const float*)d_in[5 + c * 6 + 5];
    if (big) {
      hipMemsetAsync(aux, 0, NH * sizeof(float), stream);
      edge_agg_kernel<<<(N_EDGES + 127) / 128, 256, 0, stream>>>(
          hbf, eafrag, srcp, dstp, wbase + OFF_EWT(c), eb, aux);
    } else {
      agg_gather_kernel<<<2048, 256, 0, stream>>>(
          hcur, ea, srcp, perm, rowptr, ew, eb, aux);
    }
    mlp_mfma<<<(N_NODES + 127) / 128, 256, 0, stream>>>(
        hcur, aux, wbase + OFF_LAYER(c), b1, b2, aux, hbf);
    float* tmp = hcur; hcur = aux; aux = tmp;
  }

  const float* cb1 = (const float*)d_in[24];
  const float* cb2 = (const float*)d_in[26];
  cls_mfma<<<(N_EDGES + 127) / 128, 256, 0, stream>>>(
      hbf, ea, src, dst, wbase + OFF_CW1T, wbase + OFF_CW2T, cb1, cb2, (float*)d_out);
}